// Round 2
// baseline (308.907 us; speedup 1.0000x reference)
//
#include <hip/hip_runtime.h>

#define T_STEPS 16
#define H 64
#define S_IN 25
#define A_OUT 4
#define NB 65536

__device__ __forceinline__ float fmaf_(float a, float b, float c) { return __builtin_fmaf(a, b, c); }

// Transpose W2 (64x64) and W3 (4x64) into workspace so the hot loop reads
// contiguous wave-uniform rows (scalar-load friendly).
__global__ void snn_prep(const float* __restrict__ W2, const float* __restrict__ W3,
                         float* __restrict__ W2T, float* __restrict__ W3T) {
    int i = blockIdx.x * blockDim.x + threadIdx.x;
    if (i < H * H) { int h = i >> 6, k = i & 63; W2T[k * H + h] = W2[h * H + k]; }
    if (i < A_OUT * H) { int a = i >> 6, h = i & 63; W3T[h * A_OUT + a] = W3[a * H + h]; }
}

__global__ __launch_bounds__(256) void snn_main(
    const float* __restrict__ x,
    const float* __restrict__ W1, const float* __restrict__ b1,
    const float* __restrict__ W2T, const float* __restrict__ b2,
    const float* __restrict__ W3T, const float* __restrict__ b3,
    float* __restrict__ out, int* __restrict__ g_pre, int* __restrict__ g_post)
{
#pragma clang fp contract(off)
    __shared__ int lds_pre[T_STEPS * H];
    __shared__ int lds_post[T_STEPS * A_OUT];
    for (int i = threadIdx.x; i < T_STEPS * H; i += 256) lds_pre[i] = 0;
    if (threadIdx.x < T_STEPS * A_OUT) lds_post[threadIdx.x] = 0;
    __syncthreads();

    const int b = blockIdx.x * 256 + threadIdx.x;   // one thread = one batch element
    const int lane = threadIdx.x & 63;

    // cur1 = x @ W1.T + b1  (identical every timestep)
    float cur1[H];
    {
        float xv[S_IN];
        #pragma unroll
        for (int s = 0; s < S_IN; ++s) xv[s] = x[b * S_IN + s];
        #pragma unroll
        for (int h = 0; h < H; ++h) {
            float acc = 0.0f;
            #pragma unroll
            for (int s = 0; s < S_IN; ++s) acc = fmaf_(xv[s], W1[h * S_IN + s], acc);
            cur1[h] = acc + b1[h];
        }
    }

    float m1[H], m2[H];
    float m3[A_OUT], accs[A_OUT];
    #pragma unroll
    for (int h = 0; h < H; ++h) { m1[h] = 0.0f; m2[h] = 0.0f; }
    #pragma unroll
    for (int a = 0; a < A_OUT; ++a) { m3[a] = 0.0f; accs[a] = 0.0f; }

    for (int t = 0; t < T_STEPS; ++t) {
        // ---- layer 1: membrane + spike, pack spikes into a 64-bit mask ----
        unsigned long long s1mask = 0ull;
        #pragma unroll
        for (int h = 0; h < H; ++h) {
            float m = 0.95f * m1[h];
            m = m + cur1[h];
            bool sp = m > 1.0f;
            m1[h] = sp ? (m - 1.0f) : m;
            s1mask |= ((unsigned long long)(sp ? 1u : 0u)) << h;
        }

        // ---- layer 2: m2 = beta*m2 + s1 @ W2.T (+ b2 at spike time) ----
        #pragma unroll
        for (int h = 0; h < H; ++h) m2[h] = 0.95f * m2[h];
        for (int k = 0; k < H; ++k) {                // dynamic loop: small code, W2T row uniform
            float s1f = (float)((s1mask >> k) & 1ull);
            const float* wr = W2T + k * H;
            #pragma unroll
            for (int h = 0; h < H; ++h) m2[h] = fmaf_(s1f, wr[h], m2[h]);  // exact: s1f in {0,1}
        }

        // ---- layer 2 spikes, layer 3 accumulation, pre-counts ----
        #pragma unroll
        for (int a = 0; a < A_OUT; ++a) m3[a] = 0.95f * m3[a];
        int myCnt = 0;
        #pragma unroll
        for (int h = 0; h < H; ++h) {
            float m = m2[h] + b2[h];
            bool sp = m > 1.0f;
            float s2f = sp ? 1.0f : 0.0f;
            m2[h] = m - s2f;
            #pragma unroll
            for (int a = 0; a < A_OUT; ++a)
                m3[a] = fmaf_(s2f, W3T[h * A_OUT + a], m3[a]);            // exact: s2f in {0,1}
            int cnt = (int)__popcll(__ballot(sp));    // wave-uniform spike count for hidden unit h
            myCnt = (lane == h) ? cnt : myCnt;        // lane h keeps unit h's count (v_cndmask)
        }

        // ---- layer 3 spikes + post-counts + readout accumulation ----
        int myPost = 0;
        #pragma unroll
        for (int a = 0; a < A_OUT; ++a) {
            float m = m3[a] + b3[a];
            bool sp = m > 1.0f;
            float s3f = sp ? 1.0f : 0.0f;
            m3[a] = m - s3f;
            accs[a] = accs[a] + s3f;
            int cnt = (int)__popcll(__ballot(sp));
            myPost = (lane == a) ? cnt : myPost;
        }

        atomicAdd(&lds_pre[t * H + lane], myCnt);
        if (lane < A_OUT) atomicAdd(&lds_post[t * A_OUT + lane], myPost);
    }

    // ---- per-batch softmax(acc/16) ----
    {
        float r0 = accs[0] * 0.0625f, r1 = accs[1] * 0.0625f;
        float r2 = accs[2] * 0.0625f, r3 = accs[3] * 0.0625f;
        float mx = fmaxf(fmaxf(r0, r1), fmaxf(r2, r3));
        float e0 = expf(r0 - mx), e1 = expf(r1 - mx);
        float e2 = expf(r2 - mx), e3 = expf(r3 - mx);
        float s = ((e0 + e1) + e2) + e3;
        float4 p = make_float4(e0 / s, e1 / s, e2 / s, e3 / s);
        reinterpret_cast<float4*>(out)[b] = p;
    }

    __syncthreads();
    for (int i = threadIdx.x; i < T_STEPS * H; i += 256) atomicAdd(&g_pre[i], lds_pre[i]);
    if (threadIdx.x < T_STEPS * A_OUT) atomicAdd(&g_post[threadIdx.x], lds_post[threadIdx.x]);
}

// elig_t = 0.95*elig_{t-1} + (A_PLUS-A_MINUS) * outer(post_t, pre_t); means are exact counts/B.
__global__ void snn_elig(const int* __restrict__ g_pre, const int* __restrict__ g_post,
                         const float* __restrict__ elig0, float* __restrict__ out) {
#pragma clang fp contract(off)
    int i = threadIdx.x;                 // 256 = A_OUT * H
    int a = i >> 6, h = i & 63;
    float e = elig0[i];
    const float invB = 1.0f / 65536.0f;
    for (int t = 0; t < T_STEPS; ++t) {
        float pre  = (float)g_pre[t * H + h] * invB;
        float post = (float)g_post[t * A_OUT + a] * invB;
        e = 0.95f * e + (-0.002f) * (post * pre);
    }
    out[NB * A_OUT + i] = e;
}

extern "C" void kernel_launch(void* const* d_in, const int* in_sizes, int n_in,
                              void* d_out, int out_size, void* d_ws, size_t ws_size,
                              hipStream_t stream) {
    const float* x     = (const float*)d_in[0];
    const float* W1    = (const float*)d_in[1];
    const float* b1    = (const float*)d_in[2];
    const float* W2    = (const float*)d_in[3];
    const float* b2    = (const float*)d_in[4];
    const float* W3    = (const float*)d_in[5];
    const float* b3    = (const float*)d_in[6];
    const float* elig0 = (const float*)d_in[7];
    float* out = (float*)d_out;

    char* ws = (char*)d_ws;
    int*   g_pre  = (int*)(ws);                    // 1024 ints
    int*   g_post = (int*)(ws + 4096);             // 64 ints
    float* W2T    = (float*)(ws + 8192);           // 4096 floats
    float* W3T    = (float*)(ws + 8192 + 16384);   // 256 floats

    (void)hipMemsetAsync(ws, 0, 4096 + 256, stream);  // zero count accumulators every launch
    snn_prep<<<17, 256, 0, stream>>>(W2, W3, W2T, W3T);
    snn_main<<<NB / 256, 256, 0, stream>>>(x, W1, b1, W2T, b2, W3T, b3, out, g_pre, g_post);
    snn_elig<<<1, 256, 0, stream>>>(g_pre, g_post, elig0, out);
}